// Round 1
// baseline (473.988 us; speedup 1.0000x reference)
//
#include <hip/hip_runtime.h>

#define B_ 8
#define C_ 512
#define H_ 96
#define W_ 96
#define HW_ (H_ * W_)   // 9216
#define CK_ 64

typedef __attribute__((ext_vector_type(8))) short bf16x8;
typedef __attribute__((ext_vector_type(4))) float f32x4;

// Packed bf16 weights for kernel 1 live in outbuf's dead zone: batch 0, ch 192..195.
// (out_conv phase-1 overwrites ch>=128 only AFTER kv_conv+attn have retired.)
#define WPK_OFF ((size_t)192 * HW_)

__device__ __forceinline__ short f2bf(float f) {
    union { float f; unsigned u; } v; v.f = f;
    unsigned r = v.u + 0x7fffu + ((v.u >> 16) & 1u);
    return (short)(r >> 16);
}

__device__ __forceinline__ bf16x8 cvt8(float4 a, float4 b) {
    bf16x8 s;
    s[0] = f2bf(a.x); s[1] = f2bf(a.y); s[2] = f2bf(a.z); s[3] = f2bf(a.w);
    s[4] = f2bf(b.x); s[5] = f2bf(b.y); s[6] = f2bf(b.z); s[7] = f2bf(b.w);
    return s;
}

// Intermediates live inside d_out (no d_ws usage):
//   y[b][cv][hw]  -> out channels [0..63]   (written K2, read K3)
//   kv[b][o][hw]  -> out channels [64..191] (written K1, read K2, dead after)
//   Wpk bf16      -> b=0 ch 192..195 (written K0, read K1, dead after)

// ---------------------------------------------------------------------------
// Kernel 0: pack [key1_w ; value_w] (128 x 512 fp32) -> bf16 in fragment order
//   Wpk[c8][oc][j] = W[oc][c8*8 + j],  c8 = 0..63, oc = 0..127, j = 0..7
// so a wave's af fragment is one contiguous 16B load per lane.
// ---------------------------------------------------------------------------
__global__ void pack_w_kernel(const float* __restrict__ key1_w,
                              const float* __restrict__ value_w,
                              float* __restrict__ outbuf)
{
    const int idx = blockIdx.x * 256 + threadIdx.x;   // 0..8191 = (c8, oc)
    const int c8  = idx >> 7;
    const int oc  = idx & 127;
    const float* src = (oc < 64) ? (key1_w + (size_t)oc * C_)
                                 : (value_w + (size_t)(oc - 64) * C_);
    float4 f0 = *(const float4*)(src + c8 * 8);
    float4 f1 = *(const float4*)(src + c8 * 8 + 4);
    short* wpk = (short*)(outbuf + WPK_OFF);
    *(bf16x8*)(wpk + (size_t)idx * 8) = cvt8(f0, f1);
}

// ---------------------------------------------------------------------------
// Kernel 1 (MFMA): kv[o][px] = W[o][c] @ x[c][px];  o<64: relu(key1)+b, else value+b
// Tile: M=128 oc, N=64 px, K=512, BK=32. 4 waves in 2x2 (wm: oc-half, wn: px-half).
// Barrier-free K-loop: A fragments read directly from packed bf16 W (L2-resident),
// B fragments read directly from global x (quarter-wave-coalesced dwords).
// Grid 144x8 = 1152 blocks -> ~18 waves/CU (was 576 blocks / 20% occupancy).
// ---------------------------------------------------------------------------
__global__ __launch_bounds__(256, 4)
void kv_conv_mfma(const float* __restrict__ x,
                  const float* __restrict__ key1_b,
                  const float* __restrict__ value_b,
                  float* __restrict__ outbuf)
{
    const int b    = blockIdx.y;
    const int px0  = blockIdx.x * 64;
    const int tid  = threadIdx.x;
    const int lane = tid & 63;
    const int w    = tid >> 6;
    const int wm   = w & 1;      // oc half (64)
    const int wn   = w >> 1;     // px half (32)
    const int l15  = lane & 15;
    const int q    = lane >> 4;

    __shared__ float s_bias[128];
    if (tid < 128) s_bias[tid] = (tid < 64) ? key1_b[tid] : value_b[tid - 64];
    __syncthreads();             // only barrier in the kernel

    f32x4 acc[4][2];
#pragma unroll
    for (int i = 0; i < 4; ++i)
#pragma unroll
        for (int j = 0; j < 2; ++j) acc[i][j] = (f32x4){0.f, 0.f, 0.f, 0.f};

    const short* wpk = (const short*)(outbuf + WPK_OFF);
    // lane-fixed fragment bases
    const short* apk = wpk + ((size_t)q * 128 + wm * 64 + l15) * 8;
    const float* xq  = x + (size_t)b * C_ * HW_ + (size_t)(q * 8) * HW_
                         + px0 + wn * 32 + l15;

    for (int i = 0; i < 16; ++i) {            // kc = 32*i
        bf16x8 af[4];
#pragma unroll
        for (int mt = 0; mt < 4; ++mt)
            af[mt] = *(const bf16x8*)(apk + ((size_t)i * 512 + mt * 16) * 8);

#pragma unroll
        for (int nt = 0; nt < 2; ++nt) {
            const float* xp = xq + (size_t)i * 32 * HW_ + nt * 16;
            bf16x8 bf;
#pragma unroll
            for (int j = 0; j < 8; ++j) bf[j] = f2bf(xp[(size_t)j * HW_]);
#pragma unroll
            for (int mt = 0; mt < 4; ++mt)
                acc[mt][nt] = __builtin_amdgcn_mfma_f32_16x16x32_bf16(af[mt], bf, acc[mt][nt], 0, 0, 0);
        }
    }

    // epilogue: bias (+relu for key half), store to kv region (out ch 64..191)
    float* kvb = outbuf + ((size_t)b * C_ + 64) * HW_ + px0;
#pragma unroll
    for (int mt = 0; mt < 4; ++mt) {
#pragma unroll
        for (int r = 0; r < 4; ++r) {
            int oc = wm * 64 + mt * 16 + q * 4 + r;
            float bias = s_bias[oc];
#pragma unroll
            for (int nt = 0; nt < 2; ++nt) {
                float v = acc[mt][nt][r] + bias;
                if (oc < 64) v = fmaxf(v, 0.f);
                kvb[(size_t)oc * HW_ + wn * 32 + nt * 16 + l15] = v;
            }
        }
    }
}

// ---------------------------------------------------------------------------
// Kernel 2: depthwise 3x3 + key3 1x1 + softmax + 9-tap value aggregation.
// Reads kv (ch 64..191), writes y (ch 0..63). Unchanged this round.
// ---------------------------------------------------------------------------
__global__ __launch_bounds__(256, 4)
void attn_kernel(const float* __restrict__ dw_w, const float* __restrict__ dw_b,
                 const float* __restrict__ k3_w, const float* __restrict__ k3_b,
                 float* __restrict__ outbuf)
{
    const int b  = blockIdx.y;
    const int hw = blockIdx.x * 256 + threadIdx.x;
    const int h  = hw / W_;
    const int w  = hw % W_;

    __shared__ float s_dw[CK_ * 9];
    __shared__ float s_dwb[CK_];
    __shared__ float s_k3[9 * CK_];
    __shared__ float s_k3b[16];

    for (int i = threadIdx.x; i < CK_ * 9; i += 256) {
        s_dw[i] = dw_w[i];
        s_k3[i] = k3_w[i];
    }
    if (threadIdx.x < CK_) s_dwb[threadIdx.x] = dw_b[threadIdx.x];
    if (threadIdx.x < 9)   s_k3b[threadIdx.x] = k3_b[threadIdx.x];
    __syncthreads();

    int  off[9];
    bool valid[9];
#pragma unroll
    for (int t = 0; t < 9; ++t) {
        int dy = t / 3 - 1, dx = t % 3 - 1;
        int hh = h + dy, ww = w + dx;
        valid[t] = (hh >= 0) && (hh < H_) && (ww >= 0) && (ww < W_);
        off[t]   = hh * W_ + ww;
    }

    float logits[9];
#pragma unroll
    for (int t = 0; t < 9; ++t) logits[t] = s_k3b[t];

    const float* kb = outbuf + ((size_t)b * C_ + 64) * HW_;
#pragma unroll 4
    for (int c = 0; c < CK_; ++c) {
        const float* kc = kb + (size_t)c * HW_;
        float d = s_dwb[c];
#pragma unroll
        for (int t = 0; t < 9; ++t) {
            float val = valid[t] ? kc[off[t]] : 0.f;
            d = fmaf(s_dw[c * 9 + t], val, d);
        }
#pragma unroll
        for (int t = 0; t < 9; ++t)
            logits[t] = fmaf(s_k3[t * CK_ + c], d, logits[t]);
    }

    float m = logits[0];
#pragma unroll
    for (int t = 1; t < 9; ++t) m = fmaxf(m, logits[t]);
    float e[9], s = 0.f;
#pragma unroll
    for (int t = 0; t < 9; ++t) { e[t] = __expf(logits[t] - m); s += e[t]; }
    float inv = 1.f / s;
    float wt[9];
#pragma unroll
    for (int t = 0; t < 9; ++t) wt[t] = e[t] * inv;

    const float* vb = kb + (size_t)CK_ * HW_;
    float* yb = outbuf + (size_t)b * C_ * HW_;
#pragma unroll 4
    for (int cv = 0; cv < CK_; ++cv) {
        const float* vc = vb + (size_t)cv * HW_;
        float acc = 0.f;
#pragma unroll
        for (int t = 0; t < 9; ++t) {
            float val = valid[t] ? vc[off[t]] : 0.f;
            acc = fmaf(wt[t], val, acc);
        }
        yb[(size_t)cv * HW_ + hw] = acc;
    }
}

// ---------------------------------------------------------------------------
// Kernel 3 (MFMA): out = x + out_b + out_w[512x64] @ y.  M=128/block, K=64, N=128.
// Phase 1: oc 128..511; phase 2: oc 0..127 (y self-consume, guarded by barrier).
// Unchanged this round.
// ---------------------------------------------------------------------------
__global__ __launch_bounds__(256, 4)
void out_conv_mfma(const float* __restrict__ out_w, const float* __restrict__ out_b,
                   const float* __restrict__ x, float* outbuf, int oc_base)
{
    const int b    = blockIdx.z;
    const int o0   = oc_base + blockIdx.y * 128;
    const int px0  = blockIdx.x * 128;
    const int tid  = threadIdx.x;
    const int lane = tid & 63;
    const int w    = tid >> 6;
    const int wm   = w & 1;
    const int wn   = w >> 1;
    const int l15  = lane & 15;
    const int q    = lane >> 4;

    __shared__ short Ws[128][72];   // [oc][cv] bf16, stride 72 (144 B, 16B-aligned)
    __shared__ float s_bias[128];

    {   // stage out_w tile (128 x 64) -> bf16 LDS
        int row = tid & 127, half = tid >> 7;            // half selects cv 0..31 / 32..63
        const float* wp = out_w + (size_t)(o0 + row) * CK_ + half * 32;
        float4 f0 = *(const float4*)(wp);
        float4 f1 = *(const float4*)(wp + 4);
        float4 f2 = *(const float4*)(wp + 8);
        float4 f3 = *(const float4*)(wp + 12);
        float4 f4 = *(const float4*)(wp + 16);
        float4 f5 = *(const float4*)(wp + 20);
        float4 f6 = *(const float4*)(wp + 24);
        float4 f7 = *(const float4*)(wp + 28);
        *(bf16x8*)&Ws[row][half * 32]      = cvt8(f0, f1);
        *(bf16x8*)&Ws[row][half * 32 + 8]  = cvt8(f2, f3);
        *(bf16x8*)&Ws[row][half * 32 + 16] = cvt8(f4, f5);
        *(bf16x8*)&Ws[row][half * 32 + 24] = cvt8(f6, f7);
    }
    if (tid < 128) s_bias[tid] = out_b[o0 + tid];
    __syncthreads();

    f32x4 acc[4][4];
#pragma unroll
    for (int i = 0; i < 4; ++i)
#pragma unroll
        for (int j = 0; j < 4; ++j) acc[i][j] = (f32x4){0.f, 0.f, 0.f, 0.f};

    const float* yb = outbuf + (size_t)b * C_ * HW_ + px0;   // y planes ch 0..63

#pragma unroll
    for (int kc = 0; kc < CK_; kc += 32) {
        bf16x8 af[4];
#pragma unroll
        for (int mt = 0; mt < 4; ++mt)
            af[mt] = *(bf16x8*)&Ws[wm * 64 + mt * 16 + l15][kc + q * 8];

        const float* yq = yb + (size_t)(kc + q * 8) * HW_ + wn * 64 + l15;
#pragma unroll
        for (int nt = 0; nt < 4; ++nt) {
            const float* yp = yq + nt * 16;
            bf16x8 bf;
#pragma unroll
            for (int j = 0; j < 8; ++j) bf[j] = f2bf(yp[(size_t)j * HW_]);
#pragma unroll
            for (int mt = 0; mt < 4; ++mt)
                acc[mt][nt] = __builtin_amdgcn_mfma_f32_16x16x32_bf16(af[mt], bf, acc[mt][nt], 0, 0, 0);
        }
    }

    __syncthreads();   // all y reads complete before any store (phase-2 aliasing)

    const float* xb = x + (size_t)b * C_ * HW_ + px0;
    float* ob       = outbuf + (size_t)b * C_ * HW_ + px0;
#pragma unroll
    for (int mt = 0; mt < 4; ++mt) {
#pragma unroll
        for (int r = 0; r < 4; ++r) {
            int ol   = wm * 64 + mt * 16 + q * 4 + r;
            int oc   = o0 + ol;
            float bias = s_bias[ol];
#pragma unroll
            for (int nt = 0; nt < 4; ++nt) {
                size_t idx = (size_t)oc * HW_ + wn * 64 + nt * 16 + l15;
                ob[idx] = acc[mt][nt][r] + bias + xb[idx];
            }
        }
    }
}

extern "C" void kernel_launch(void* const* d_in, const int* in_sizes, int n_in,
                              void* d_out, int out_size, void* d_ws, size_t ws_size,
                              hipStream_t stream)
{
    const float* x       = (const float*)d_in[0];
    const float* key1_w  = (const float*)d_in[1];
    const float* key1_b  = (const float*)d_in[2];
    const float* dw_w    = (const float*)d_in[3];
    const float* dw_b    = (const float*)d_in[4];
    const float* k3_w    = (const float*)d_in[5];
    const float* k3_b    = (const float*)d_in[6];
    const float* value_w = (const float*)d_in[7];
    const float* value_b = (const float*)d_in[8];
    const float* out_w   = (const float*)d_in[9];
    const float* out_b   = (const float*)d_in[10];
    float* out = (float*)d_out;

    // K0: pack kv weights to bf16 fragment order (stash in outbuf dead zone)
    pack_w_kernel<<<dim3(32), dim3(256), 0, stream>>>(key1_w, value_w, out);

    // K1: kv 1x1 convs, barrier-free MFMA loop
    dim3 g1(HW_ / 64, B_);
    kv_conv_mfma<<<g1, dim3(256), 0, stream>>>(x, key1_b, value_b, out);

    dim3 g2(HW_ / 256, B_);
    attn_kernel<<<g2, dim3(256), 0, stream>>>(dw_w, dw_b, k3_w, k3_b, out);

    dim3 g3(HW_ / 128, 3, B_);
    out_conv_mfma<<<g3, dim3(256), 0, stream>>>(out_w, out_b, x, out, 128);

    dim3 g4(HW_ / 128, 1, B_);
    out_conv_mfma<<<g4, dim3(256), 0, stream>>>(out_w, out_b, x, out, 0);
}

// Round 2
// 467.644 us; speedup vs baseline: 1.0136x; 1.0136x over previous
//
#include <hip/hip_runtime.h>

#define B_ 8
#define C_ 512
#define H_ 96
#define W_ 96
#define HW_ (H_ * W_)   // 9216
#define CK_ 64

typedef __attribute__((ext_vector_type(8))) short bf16x8;
typedef __attribute__((ext_vector_type(4))) float f32x4;

// outbuf channel map per batch b (fp32 plane units):
//   ch   0.. 63 : y            (written K2/attn, read K3/out_conv)
//   ch  64..191 : kv (k|v)     (written K1, read K2, dead after)
//   ch 192..447 : xpk bf16     (written pack_x, read K1, dead after; clobbered by out_conv p1)
//   b=0 ch 448..452 : wpk bf16 (written pack_w, read K1, dead after)
#define XPK_CH 192
#define WPK_OFF ((size_t)448 * HW_)

__device__ __forceinline__ short f2bf(float f) {
    union { float f; unsigned u; } v; v.f = f;
    unsigned r = v.u + 0x7fffu + ((v.u >> 16) & 1u);
    return (short)(r >> 16);
}

__device__ __forceinline__ bf16x8 cvt8(float4 a, float4 b) {
    bf16x8 s;
    s[0] = f2bf(a.x); s[1] = f2bf(a.y); s[2] = f2bf(a.z); s[3] = f2bf(a.w);
    s[4] = f2bf(b.x); s[5] = f2bf(b.y); s[6] = f2bf(b.z); s[7] = f2bf(b.w);
    return s;
}

// ---------------------------------------------------------------------------
// Kernel 0a: pack [key1_w ; value_w] (128 x 512 fp32) -> bf16 fragment order
//   wpk[c8][oc][j] = W[oc][c8*8 + j]
// ---------------------------------------------------------------------------
__global__ void pack_w_kernel(const float* __restrict__ key1_w,
                              const float* __restrict__ value_w,
                              float* __restrict__ outbuf)
{
    const int idx = blockIdx.x * 256 + threadIdx.x;   // 0..8191 = (c8, oc)
    const int c8  = idx >> 7;
    const int oc  = idx & 127;
    const float* src = (oc < 64) ? (key1_w + (size_t)oc * C_)
                                 : (value_w + (size_t)(oc - 64) * C_);
    float4 f0 = *(const float4*)(src + c8 * 8);
    float4 f1 = *(const float4*)(src + c8 * 8 + 4);
    short* wpk = (short*)(outbuf + WPK_OFF);
    *(bf16x8*)(wpk + (size_t)idx * 8) = cvt8(f0, f1);
}

// ---------------------------------------------------------------------------
// Kernel 0b: pack x (fp32 [b][c][px]) -> bf16 fragment order
//   xpk[b][c8][px][j] = bf16(x[b][c8*8 + j][px]),  c8 = 0..63
// Reads coalesced (lane = px), writes 16B/thread contiguous. Streaming pass.
// ---------------------------------------------------------------------------
__global__ __launch_bounds__(256)
void pack_x_kernel(const float* __restrict__ x, float* __restrict__ outbuf)
{
    const int px = blockIdx.x * 256 + threadIdx.x;   // grid.x = 36
    const int c8 = blockIdx.y;                        // 0..63
    const int b  = blockIdx.z;                        // 0..7
    const float* src = x + ((size_t)b * C_ + c8 * 8) * HW_ + px;
    float f[8];
#pragma unroll
    for (int j = 0; j < 8; ++j) f[j] = src[(size_t)j * HW_];
    bf16x8 s;
#pragma unroll
    for (int j = 0; j < 8; ++j) s[j] = f2bf(f[j]);
    short* xpk = (short*)(outbuf + (size_t)b * C_ * HW_ + (size_t)XPK_CH * HW_);
    *(bf16x8*)(xpk + ((size_t)c8 * HW_ + px) * 8) = s;
}

// ---------------------------------------------------------------------------
// Kernel 1 (MFMA): kv[o][px] = W[o][c] @ x[c][px];  o<64: relu(key1)+b, else value+b
// Tile: M=128 oc, N=64 px, K=512. 4 waves 2x2. Barrier-free K-loop, all operand
// loads are single global_load_dwordx4 from pre-packed bf16 (wpk L2-resident,
// xpk streamed). No f2bf in the loop, no LDS in the loop.
// ---------------------------------------------------------------------------
__global__ __launch_bounds__(256, 4)
void kv_conv_mfma(const float* __restrict__ key1_b,
                  const float* __restrict__ value_b,
                  float* __restrict__ outbuf)
{
    const int b    = blockIdx.y;
    const int px0  = blockIdx.x * 64;
    const int tid  = threadIdx.x;
    const int lane = tid & 63;
    const int w    = tid >> 6;
    const int wm   = w & 1;      // oc half (64)
    const int wn   = w >> 1;     // px half (32)
    const int l15  = lane & 15;
    const int q    = lane >> 4;

    __shared__ float s_bias[128];
    if (tid < 128) s_bias[tid] = (tid < 64) ? key1_b[tid] : value_b[tid - 64];
    __syncthreads();             // only barrier in the kernel

    f32x4 acc[4][2];
#pragma unroll
    for (int i = 0; i < 4; ++i)
#pragma unroll
        for (int j = 0; j < 2; ++j) acc[i][j] = (f32x4){0.f, 0.f, 0.f, 0.f};

    const short* wpk = (const short*)(outbuf + WPK_OFF);
    const short* xpk = (const short*)(outbuf + (size_t)b * C_ * HW_ + (size_t)XPK_CH * HW_);
    // lane-fixed fragment bases (c8 = i*4 + q for both operands)
    const short* apk = wpk + ((size_t)q * 128 + wm * 64 + l15) * 8;
    const short* bpk = xpk + ((size_t)q * HW_ + px0 + wn * 32 + l15) * 8;

    for (int i = 0; i < 16; ++i) {            // kc = 32*i
        bf16x8 af[4];
#pragma unroll
        for (int mt = 0; mt < 4; ++mt)
            af[mt] = *(const bf16x8*)(apk + ((size_t)i * 512 + mt * 16) * 8);
        bf16x8 bf[2];
#pragma unroll
        for (int nt = 0; nt < 2; ++nt)
            bf[nt] = *(const bf16x8*)(bpk + ((size_t)(i * 4) * HW_ + nt * 16) * 8);
#pragma unroll
        for (int nt = 0; nt < 2; ++nt)
#pragma unroll
            for (int mt = 0; mt < 4; ++mt)
                acc[mt][nt] = __builtin_amdgcn_mfma_f32_16x16x32_bf16(af[mt], bf[nt], acc[mt][nt], 0, 0, 0);
    }

    // epilogue: bias (+relu for key half), store to kv region (out ch 64..191)
    float* kvb = outbuf + ((size_t)b * C_ + 64) * HW_ + px0;
#pragma unroll
    for (int mt = 0; mt < 4; ++mt) {
#pragma unroll
        for (int r = 0; r < 4; ++r) {
            int oc = wm * 64 + mt * 16 + q * 4 + r;
            float bias = s_bias[oc];
#pragma unroll
            for (int nt = 0; nt < 2; ++nt) {
                float v = acc[mt][nt][r] + bias;
                if (oc < 64) v = fmaxf(v, 0.f);
                kvb[(size_t)oc * HW_ + wn * 32 + nt * 16 + l15] = v;
            }
        }
    }
}

// ---------------------------------------------------------------------------
// Kernel 2: depthwise 3x3 + key3 1x1 + softmax + 9-tap value aggregation.
// v2: 4x channel-split parallelism. Block = 64 px, 4 waves; wave w reduces
// key channels [16w,16w+16) into partial logits, LDS-reduce, per-thread
// softmax, then wave w produces value channels [16w,16w+16).
// Grid 144x8 = 1152 blocks x 4 waves = 18 waves/CU (was 4.5).
// ---------------------------------------------------------------------------
__global__ __launch_bounds__(256, 4)
void attn_kernel(const float* __restrict__ dw_w, const float* __restrict__ dw_b,
                 const float* __restrict__ k3_w, const float* __restrict__ k3_b,
                 float* __restrict__ outbuf)
{
    const int b    = blockIdx.y;
    const int px0  = blockIdx.x * 64;
    const int tid  = threadIdx.x;
    const int lane = tid & 63;
    const int wv   = tid >> 6;          // 0..3
    const int hw   = px0 + lane;
    const int h    = hw / W_;
    const int w    = hw % W_;

    __shared__ float s_dw[CK_ * 9];
    __shared__ float s_dwb[CK_];
    __shared__ float s_k3[9 * CK_];
    __shared__ float s_k3b[16];
    __shared__ float s_part[4][9][64];

    for (int i = tid; i < CK_ * 9; i += 256) {
        s_dw[i] = dw_w[i];
        s_k3[i] = k3_w[i];
    }
    if (tid < CK_) s_dwb[tid] = dw_b[tid];
    if (tid < 9)   s_k3b[tid] = k3_b[tid];
    __syncthreads();

    int  off[9];
    bool valid[9];
#pragma unroll
    for (int t = 0; t < 9; ++t) {
        int dy = t / 3 - 1, dx = t % 3 - 1;
        int hh = h + dy, ww = w + dx;
        valid[t] = (hh >= 0) && (hh < H_) && (ww >= 0) && (ww < W_);
        off[t]   = hh * W_ + ww;
    }

    // Phase A: partial logits over this wave's 16 key channels
    float part[9];
#pragma unroll
    for (int t = 0; t < 9; ++t) part[t] = 0.f;

    const float* kb = outbuf + ((size_t)b * C_ + 64) * HW_;
#pragma unroll 4
    for (int ci = 0; ci < 16; ++ci) {
        const int c = wv * 16 + ci;
        const float* kc = kb + (size_t)c * HW_;
        float d = s_dwb[c];
#pragma unroll
        for (int t = 0; t < 9; ++t) {
            float val = valid[t] ? kc[off[t]] : 0.f;
            d = fmaf(s_dw[c * 9 + t], val, d);
        }
#pragma unroll
        for (int t = 0; t < 9; ++t)
            part[t] = fmaf(s_k3[t * CK_ + c], d, part[t]);
    }
#pragma unroll
    for (int t = 0; t < 9; ++t) s_part[wv][t][lane] = part[t];
    __syncthreads();

    // reduce partials (each wave redundantly, for its own px=lane)
    float logits[9];
#pragma unroll
    for (int t = 0; t < 9; ++t)
        logits[t] = s_k3b[t] + s_part[0][t][lane] + s_part[1][t][lane]
                             + s_part[2][t][lane] + s_part[3][t][lane];

    float m = logits[0];
#pragma unroll
    for (int t = 1; t < 9; ++t) m = fmaxf(m, logits[t]);
    float e[9], s = 0.f;
#pragma unroll
    for (int t = 0; t < 9; ++t) { e[t] = __expf(logits[t] - m); s += e[t]; }
    float inv = 1.f / s;
    float wt[9];
#pragma unroll
    for (int t = 0; t < 9; ++t) wt[t] = e[t] * inv;

    // Phase B: this wave's 16 value channels
    const float* vb = kb + (size_t)CK_ * HW_;
    float* yb = outbuf + (size_t)b * C_ * HW_;
#pragma unroll 4
    for (int ci = 0; ci < 16; ++ci) {
        const int cv = wv * 16 + ci;
        const float* vc = vb + (size_t)cv * HW_;
        float acc = 0.f;
#pragma unroll
        for (int t = 0; t < 9; ++t) {
            float val = valid[t] ? vc[off[t]] : 0.f;
            acc = fmaf(wt[t], val, acc);
        }
        yb[(size_t)cv * HW_ + hw] = acc;
    }
}

// ---------------------------------------------------------------------------
// Kernel 3 (MFMA): out = x + out_b + out_w[512x64] @ y.  M=128/block, K=64, N=128.
// Phase 1: oc 128..511; phase 2: oc 0..127 (y self-consume, guarded by barrier).
// Unchanged this round.
// ---------------------------------------------------------------------------
__global__ __launch_bounds__(256, 4)
void out_conv_mfma(const float* __restrict__ out_w, const float* __restrict__ out_b,
                   const float* __restrict__ x, float* outbuf, int oc_base)
{
    const int b    = blockIdx.z;
    const int o0   = oc_base + blockIdx.y * 128;
    const int px0  = blockIdx.x * 128;
    const int tid  = threadIdx.x;
    const int lane = tid & 63;
    const int w    = tid >> 6;
    const int wm   = w & 1;
    const int wn   = w >> 1;
    const int l15  = lane & 15;
    const int q    = lane >> 4;

    __shared__ short Ws[128][72];   // [oc][cv] bf16, stride 72 (144 B, 16B-aligned)
    __shared__ float s_bias[128];

    {   // stage out_w tile (128 x 64) -> bf16 LDS
        int row = tid & 127, half = tid >> 7;            // half selects cv 0..31 / 32..63
        const float* wp = out_w + (size_t)(o0 + row) * CK_ + half * 32;
        float4 f0 = *(const float4*)(wp);
        float4 f1 = *(const float4*)(wp + 4);
        float4 f2 = *(const float4*)(wp + 8);
        float4 f3 = *(const float4*)(wp + 12);
        float4 f4 = *(const float4*)(wp + 16);
        float4 f5 = *(const float4*)(wp + 20);
        float4 f6 = *(const float4*)(wp + 24);
        float4 f7 = *(const float4*)(wp + 28);
        *(bf16x8*)&Ws[row][half * 32]      = cvt8(f0, f1);
        *(bf16x8*)&Ws[row][half * 32 + 8]  = cvt8(f2, f3);
        *(bf16x8*)&Ws[row][half * 32 + 16] = cvt8(f4, f5);
        *(bf16x8*)&Ws[row][half * 32 + 24] = cvt8(f6, f7);
    }
    if (tid < 128) s_bias[tid] = out_b[o0 + tid];
    __syncthreads();

    f32x4 acc[4][4];
#pragma unroll
    for (int i = 0; i < 4; ++i)
#pragma unroll
        for (int j = 0; j < 4; ++j) acc[i][j] = (f32x4){0.f, 0.f, 0.f, 0.f};

    const float* yb = outbuf + (size_t)b * C_ * HW_ + px0;   // y planes ch 0..63

#pragma unroll
    for (int kc = 0; kc < CK_; kc += 32) {
        bf16x8 af[4];
#pragma unroll
        for (int mt = 0; mt < 4; ++mt)
            af[mt] = *(bf16x8*)&Ws[wm * 64 + mt * 16 + l15][kc + q * 8];

        const float* yq = yb + (size_t)(kc + q * 8) * HW_ + wn * 64 + l15;
#pragma unroll
        for (int nt = 0; nt < 4; ++nt) {
            const float* yp = yq + nt * 16;
            bf16x8 bf;
#pragma unroll
            for (int j = 0; j < 8; ++j) bf[j] = f2bf(yp[(size_t)j * HW_]);
#pragma unroll
            for (int mt = 0; mt < 4; ++mt)
                acc[mt][nt] = __builtin_amdgcn_mfma_f32_16x16x32_bf16(af[mt], bf, acc[mt][nt], 0, 0, 0);
        }
    }

    __syncthreads();   // all y reads complete before any store (phase-2 aliasing)

    const float* xb = x + (size_t)b * C_ * HW_ + px0;
    float* ob       = outbuf + (size_t)b * C_ * HW_ + px0;
#pragma unroll
    for (int mt = 0; mt < 4; ++mt) {
#pragma unroll
        for (int r = 0; r < 4; ++r) {
            int ol   = wm * 64 + mt * 16 + q * 4 + r;
            int oc   = o0 + ol;
            float bias = s_bias[ol];
#pragma unroll
            for (int nt = 0; nt < 4; ++nt) {
                size_t idx = (size_t)oc * HW_ + wn * 64 + nt * 16 + l15;
                ob[idx] = acc[mt][nt][r] + bias + xb[idx];
            }
        }
    }
}

extern "C" void kernel_launch(void* const* d_in, const int* in_sizes, int n_in,
                              void* d_out, int out_size, void* d_ws, size_t ws_size,
                              hipStream_t stream)
{
    const float* x       = (const float*)d_in[0];
    const float* key1_w  = (const float*)d_in[1];
    const float* key1_b  = (const float*)d_in[2];
    const float* dw_w    = (const float*)d_in[3];
    const float* dw_b    = (const float*)d_in[4];
    const float* k3_w    = (const float*)d_in[5];
    const float* k3_b    = (const float*)d_in[6];
    const float* value_w = (const float*)d_in[7];
    const float* value_b = (const float*)d_in[8];
    const float* out_w   = (const float*)d_in[9];
    const float* out_b   = (const float*)d_in[10];
    float* out = (float*)d_out;

    // K0: pack weights + x into bf16 fragment order (outbuf dead zones)
    pack_w_kernel<<<dim3(32), dim3(256), 0, stream>>>(key1_w, value_w, out);
    pack_x_kernel<<<dim3(HW_ / 256, 64, B_), dim3(256), 0, stream>>>(x, out);

    // K1: kv 1x1 convs, barrier-free fully-vectorized MFMA loop
    dim3 g1(HW_ / 64, B_);
    kv_conv_mfma<<<g1, dim3(256), 0, stream>>>(key1_b, value_b, out);

    // K2: attention, channel-split across waves
    dim3 g2(HW_ / 64, B_);
    attn_kernel<<<g2, dim3(256), 0, stream>>>(dw_w, dw_b, k3_w, k3_b, out);

    // K3: output projection + residual
    dim3 g3(HW_ / 128, 3, B_);
    out_conv_mfma<<<g3, dim3(256), 0, stream>>>(out_w, out_b, x, out, 128);

    dim3 g4(HW_ / 128, 1, B_);
    out_conv_mfma<<<g4, dim3(256), 0, stream>>>(out_w, out_b, x, out, 0);
}

// Round 3
// 426.561 us; speedup vs baseline: 1.1112x; 1.0963x over previous
//
#include <hip/hip_runtime.h>

#define B_ 8
#define C_ 512
#define H_ 96
#define W_ 96
#define HW_ (H_ * W_)   // 9216
#define CK_ 64

typedef __attribute__((ext_vector_type(8))) short bf16x8;
typedef __attribute__((ext_vector_type(4))) float f32x4;

// outbuf channel map per batch b (fp32 plane units):
//   ch   0.. 63 : y            (written K2/attn, read K3/out_conv)
//   ch  64..191 : kv (k|v)     (written K1, read K2, dead after)
//   ch 192..447 : xpk bf16     (written pack_x, read K1, dead after; clobbered by out_conv p1)
//   b=0 ch 448..452 : wpk bf16 (written pack_w, read K1, dead after)
#define XPK_CH 192
#define WPK_OFF ((size_t)448 * HW_)

__device__ __forceinline__ short f2bf(float f) {
    union { float f; unsigned u; } v; v.f = f;
    unsigned r = v.u + 0x7fffu + ((v.u >> 16) & 1u);
    return (short)(r >> 16);
}

__device__ __forceinline__ bf16x8 cvt8(float4 a, float4 b) {
    bf16x8 s;
    s[0] = f2bf(a.x); s[1] = f2bf(a.y); s[2] = f2bf(a.z); s[3] = f2bf(a.w);
    s[4] = f2bf(b.x); s[5] = f2bf(b.y); s[6] = f2bf(b.z); s[7] = f2bf(b.w);
    return s;
}

// ---------------------------------------------------------------------------
// Kernel 0a: pack [key1_w ; value_w] (128 x 512 fp32) -> bf16 fragment order
// ---------------------------------------------------------------------------
__global__ void pack_w_kernel(const float* __restrict__ key1_w,
                              const float* __restrict__ value_w,
                              float* __restrict__ outbuf)
{
    const int idx = blockIdx.x * 256 + threadIdx.x;   // 0..8191 = (c8, oc)
    const int c8  = idx >> 7;
    const int oc  = idx & 127;
    const float* src = (oc < 64) ? (key1_w + (size_t)oc * C_)
                                 : (value_w + (size_t)(oc - 64) * C_);
    float4 f0 = *(const float4*)(src + c8 * 8);
    float4 f1 = *(const float4*)(src + c8 * 8 + 4);
    short* wpk = (short*)(outbuf + WPK_OFF);
    *(bf16x8*)(wpk + (size_t)idx * 8) = cvt8(f0, f1);
}

// ---------------------------------------------------------------------------
// Kernel 0b: pack x (fp32 [b][c][px]) -> bf16 fragment order
//   xpk[b][c8][px][j] = bf16(x[b][c8*8 + j][px]),  c8 = 0..63
// ---------------------------------------------------------------------------
__global__ __launch_bounds__(256)
void pack_x_kernel(const float* __restrict__ x, float* __restrict__ outbuf)
{
    const int px = blockIdx.x * 256 + threadIdx.x;   // grid.x = 36
    const int c8 = blockIdx.y;                        // 0..63
    const int b  = blockIdx.z;                        // 0..7
    const float* src = x + ((size_t)b * C_ + c8 * 8) * HW_ + px;
    float f[8];
#pragma unroll
    for (int j = 0; j < 8; ++j) f[j] = src[(size_t)j * HW_];
    bf16x8 s;
#pragma unroll
    for (int j = 0; j < 8; ++j) s[j] = f2bf(f[j]);
    short* xpk = (short*)(outbuf + (size_t)b * C_ * HW_ + (size_t)XPK_CH * HW_);
    *(bf16x8*)(xpk + ((size_t)c8 * HW_ + px) * 8) = s;
}

// ---------------------------------------------------------------------------
// Kernel 1 (MFMA): kv[o][px] = W[o][c] @ x[c][px];  o<64: relu(key1)+b, else value+b
// Unchanged this round.
// ---------------------------------------------------------------------------
__global__ __launch_bounds__(256, 4)
void kv_conv_mfma(const float* __restrict__ key1_b,
                  const float* __restrict__ value_b,
                  float* __restrict__ outbuf)
{
    const int b    = blockIdx.y;
    const int px0  = blockIdx.x * 64;
    const int tid  = threadIdx.x;
    const int lane = tid & 63;
    const int w    = tid >> 6;
    const int wm   = w & 1;      // oc half (64)
    const int wn   = w >> 1;     // px half (32)
    const int l15  = lane & 15;
    const int q    = lane >> 4;

    __shared__ float s_bias[128];
    if (tid < 128) s_bias[tid] = (tid < 64) ? key1_b[tid] : value_b[tid - 64];
    __syncthreads();             // only barrier in the kernel

    f32x4 acc[4][2];
#pragma unroll
    for (int i = 0; i < 4; ++i)
#pragma unroll
        for (int j = 0; j < 2; ++j) acc[i][j] = (f32x4){0.f, 0.f, 0.f, 0.f};

    const short* wpk = (const short*)(outbuf + WPK_OFF);
    const short* xpk = (const short*)(outbuf + (size_t)b * C_ * HW_ + (size_t)XPK_CH * HW_);
    const short* apk = wpk + ((size_t)q * 128 + wm * 64 + l15) * 8;
    const short* bpk = xpk + ((size_t)q * HW_ + px0 + wn * 32 + l15) * 8;

    for (int i = 0; i < 16; ++i) {            // kc = 32*i
        bf16x8 af[4];
#pragma unroll
        for (int mt = 0; mt < 4; ++mt)
            af[mt] = *(const bf16x8*)(apk + ((size_t)i * 512 + mt * 16) * 8);
        bf16x8 bf[2];
#pragma unroll
        for (int nt = 0; nt < 2; ++nt)
            bf[nt] = *(const bf16x8*)(bpk + ((size_t)(i * 4) * HW_ + nt * 16) * 8);
#pragma unroll
        for (int nt = 0; nt < 2; ++nt)
#pragma unroll
            for (int mt = 0; mt < 4; ++mt)
                acc[mt][nt] = __builtin_amdgcn_mfma_f32_16x16x32_bf16(af[mt], bf[nt], acc[mt][nt], 0, 0, 0);
    }

    float* kvb = outbuf + ((size_t)b * C_ + 64) * HW_ + px0;
#pragma unroll
    for (int mt = 0; mt < 4; ++mt) {
#pragma unroll
        for (int r = 0; r < 4; ++r) {
            int oc = wm * 64 + mt * 16 + q * 4 + r;
            float bias = s_bias[oc];
#pragma unroll
            for (int nt = 0; nt < 2; ++nt) {
                float v = acc[mt][nt][r] + bias;
                if (oc < 64) v = fmaxf(v, 0.f);
                kvb[(size_t)oc * HW_ + wn * 32 + nt * 16 + l15] = v;
            }
        }
    }
}

// ---------------------------------------------------------------------------
// Kernel 2: depthwise 3x3 + key3 1x1 + softmax + 9-tap value aggregation.
// Unchanged this round.
// ---------------------------------------------------------------------------
__global__ __launch_bounds__(256, 4)
void attn_kernel(const float* __restrict__ dw_w, const float* __restrict__ dw_b,
                 const float* __restrict__ k3_w, const float* __restrict__ k3_b,
                 float* __restrict__ outbuf)
{
    const int b    = blockIdx.y;
    const int px0  = blockIdx.x * 64;
    const int tid  = threadIdx.x;
    const int lane = tid & 63;
    const int wv   = tid >> 6;          // 0..3
    const int hw   = px0 + lane;
    const int h    = hw / W_;
    const int w    = hw % W_;

    __shared__ float s_dw[CK_ * 9];
    __shared__ float s_dwb[CK_];
    __shared__ float s_k3[9 * CK_];
    __shared__ float s_k3b[16];
    __shared__ float s_part[4][9][64];

    for (int i = tid; i < CK_ * 9; i += 256) {
        s_dw[i] = dw_w[i];
        s_k3[i] = k3_w[i];
    }
    if (tid < CK_) s_dwb[tid] = dw_b[tid];
    if (tid < 9)   s_k3b[tid] = k3_b[tid];
    __syncthreads();

    int  off[9];
    bool valid[9];
#pragma unroll
    for (int t = 0; t < 9; ++t) {
        int dy = t / 3 - 1, dx = t % 3 - 1;
        int hh = h + dy, ww = w + dx;
        valid[t] = (hh >= 0) && (hh < H_) && (ww >= 0) && (ww < W_);
        off[t]   = hh * W_ + ww;
    }

    float part[9];
#pragma unroll
    for (int t = 0; t < 9; ++t) part[t] = 0.f;

    const float* kb = outbuf + ((size_t)b * C_ + 64) * HW_;
#pragma unroll 4
    for (int ci = 0; ci < 16; ++ci) {
        const int c = wv * 16 + ci;
        const float* kc = kb + (size_t)c * HW_;
        float d = s_dwb[c];
#pragma unroll
        for (int t = 0; t < 9; ++t) {
            float val = valid[t] ? kc[off[t]] : 0.f;
            d = fmaf(s_dw[c * 9 + t], val, d);
        }
#pragma unroll
        for (int t = 0; t < 9; ++t)
            part[t] = fmaf(s_k3[t * CK_ + c], d, part[t]);
    }
#pragma unroll
    for (int t = 0; t < 9; ++t) s_part[wv][t][lane] = part[t];
    __syncthreads();

    float logits[9];
#pragma unroll
    for (int t = 0; t < 9; ++t)
        logits[t] = s_k3b[t] + s_part[0][t][lane] + s_part[1][t][lane]
                             + s_part[2][t][lane] + s_part[3][t][lane];

    float m = logits[0];
#pragma unroll
    for (int t = 1; t < 9; ++t) m = fmaxf(m, logits[t]);
    float e[9], s = 0.f;
#pragma unroll
    for (int t = 0; t < 9; ++t) { e[t] = __expf(logits[t] - m); s += e[t]; }
    float inv = 1.f / s;
    float wt[9];
#pragma unroll
    for (int t = 0; t < 9; ++t) wt[t] = e[t] * inv;

    const float* vb = kb + (size_t)CK_ * HW_;
    float* yb = outbuf + (size_t)b * C_ * HW_;
#pragma unroll 4
    for (int ci = 0; ci < 16; ++ci) {
        const int cv = wv * 16 + ci;
        const float* vc = vb + (size_t)cv * HW_;
        float acc = 0.f;
#pragma unroll
        for (int t = 0; t < 9; ++t) {
            float val = valid[t] ? vc[off[t]] : 0.f;
            acc = fmaf(wt[t], val, acc);
        }
        yb[(size_t)cv * HW_ + hw] = acc;
    }
}

// ---------------------------------------------------------------------------
// Kernel 3 (MFMA): out = x + out_b + out_w[512x64] @ y.  M=128/block, K=64.
// v3: register-batched. All 64 y-gather dwords loaded into registers up front
// (one wide vmcnt wait instead of ~11 serial batches at 52 VGPRs), epilogue x
// loads batched before the barrier. launch_bounds(256,2) -> VGPR cap 256.
// NT=4: N=128 (phase 1, oc 128..511, no barrier needed - writes disjoint of y).
// NT=2: N=64  (phase 2, oc 0..127, 2x grid, barrier guards y self-clobber).
// ---------------------------------------------------------------------------
template<int NT>
__global__ __launch_bounds__(256, 2)
void out_conv_mfma(const float* __restrict__ out_w, const float* __restrict__ out_b,
                   const float* __restrict__ x, float* __restrict__ outbuf, int oc_base)
{
    const int b    = blockIdx.z;
    const int o0   = oc_base + blockIdx.y * 128;
    const int px0  = blockIdx.x * (NT * 32);
    const int tid  = threadIdx.x;
    const int lane = tid & 63;
    const int w    = tid >> 6;
    const int wm   = w & 1;
    const int wn   = w >> 1;
    const int l15  = lane & 15;
    const int q    = lane >> 4;

    __shared__ short Ws[128][72];   // [oc][cv] bf16, stride 72 (144 B, 16B-aligned)
    __shared__ float s_bias[128];

    {   // stage out_w tile (128 x 64) -> bf16 LDS
        int row = tid & 127, half = tid >> 7;
        const float* wp = out_w + (size_t)(o0 + row) * CK_ + half * 32;
        float4 f0 = *(const float4*)(wp);
        float4 f1 = *(const float4*)(wp + 4);
        float4 f2 = *(const float4*)(wp + 8);
        float4 f3 = *(const float4*)(wp + 12);
        float4 f4 = *(const float4*)(wp + 16);
        float4 f5 = *(const float4*)(wp + 20);
        float4 f6 = *(const float4*)(wp + 24);
        float4 f7 = *(const float4*)(wp + 28);
        *(bf16x8*)&Ws[row][half * 32]      = cvt8(f0, f1);
        *(bf16x8*)&Ws[row][half * 32 + 8]  = cvt8(f2, f3);
        *(bf16x8*)&Ws[row][half * 32 + 16] = cvt8(f4, f5);
        *(bf16x8*)&Ws[row][half * 32 + 24] = cvt8(f6, f7);
    }
    if (tid < 128) s_bias[tid] = out_b[o0 + tid];
    __syncthreads();

    // af fragments for both k-steps
    bf16x8 af[2][4];
#pragma unroll
    for (int kc2 = 0; kc2 < 2; ++kc2)
#pragma unroll
        for (int mt = 0; mt < 4; ++mt)
            af[kc2][mt] = *(bf16x8*)&Ws[wm * 64 + mt * 16 + l15][kc2 * 32 + q * 8];

    // batch-gather ALL y operand dwords (2 k-steps x NT n-tiles x 8)
    const float* yb = outbuf + (size_t)b * C_ * HW_ + px0;
    float yv[2][NT][8];
#pragma unroll
    for (int kc2 = 0; kc2 < 2; ++kc2)
#pragma unroll
        for (int nt = 0; nt < NT; ++nt) {
            const float* yp = yb + (size_t)(kc2 * 32 + q * 8) * HW_
                                 + wn * (NT * 16) + nt * 16 + l15;
#pragma unroll
            for (int j = 0; j < 8; ++j) yv[kc2][nt][j] = yp[(size_t)j * HW_];
        }

    f32x4 acc[4][NT];
#pragma unroll
    for (int i = 0; i < 4; ++i)
#pragma unroll
        for (int j = 0; j < NT; ++j) acc[i][j] = (f32x4){0.f, 0.f, 0.f, 0.f};

#pragma unroll
    for (int kc2 = 0; kc2 < 2; ++kc2)
#pragma unroll
        for (int nt = 0; nt < NT; ++nt) {
            bf16x8 bf;
#pragma unroll
            for (int j = 0; j < 8; ++j) bf[j] = f2bf(yv[kc2][nt][j]);
#pragma unroll
            for (int mt = 0; mt < 4; ++mt)
                acc[mt][nt] = __builtin_amdgcn_mfma_f32_16x16x32_bf16(af[kc2][mt], bf, acc[mt][nt], 0, 0, 0);
        }

    // batch epilogue x loads (read-only input - safe to hoist above barrier)
    const float* xb = x + (size_t)b * C_ * HW_ + px0;
    float xv[4][4][NT];
#pragma unroll
    for (int mt = 0; mt < 4; ++mt)
#pragma unroll
        for (int r = 0; r < 4; ++r) {
            int oc = o0 + wm * 64 + mt * 16 + q * 4 + r;
#pragma unroll
            for (int nt = 0; nt < NT; ++nt)
                xv[mt][r][nt] = xb[(size_t)oc * HW_ + wn * (NT * 16) + nt * 16 + l15];
        }

    if (NT == 2) __syncthreads();   // phase 2 only: all y reads before any store

    float* ob = outbuf + (size_t)b * C_ * HW_ + px0;
#pragma unroll
    for (int mt = 0; mt < 4; ++mt) {
#pragma unroll
        for (int r = 0; r < 4; ++r) {
            int ol   = wm * 64 + mt * 16 + q * 4 + r;
            int oc   = o0 + ol;
            float bias = s_bias[ol];
#pragma unroll
            for (int nt = 0; nt < NT; ++nt) {
                size_t idx = (size_t)oc * HW_ + wn * (NT * 16) + nt * 16 + l15;
                ob[idx] = acc[mt][nt][r] + bias + xv[mt][r][nt];
            }
        }
    }
}

extern "C" void kernel_launch(void* const* d_in, const int* in_sizes, int n_in,
                              void* d_out, int out_size, void* d_ws, size_t ws_size,
                              hipStream_t stream)
{
    const float* x       = (const float*)d_in[0];
    const float* key1_w  = (const float*)d_in[1];
    const float* key1_b  = (const float*)d_in[2];
    const float* dw_w    = (const float*)d_in[3];
    const float* dw_b    = (const float*)d_in[4];
    const float* k3_w    = (const float*)d_in[5];
    const float* k3_b    = (const float*)d_in[6];
    const float* value_w = (const float*)d_in[7];
    const float* value_b = (const float*)d_in[8];
    const float* out_w   = (const float*)d_in[9];
    const float* out_b   = (const float*)d_in[10];
    float* out = (float*)d_out;

    // K0: pack weights + x into bf16 fragment order (outbuf dead zones)
    pack_w_kernel<<<dim3(32), dim3(256), 0, stream>>>(key1_w, value_w, out);
    pack_x_kernel<<<dim3(HW_ / 256, 64, B_), dim3(256), 0, stream>>>(x, out);

    // K1: kv 1x1 convs, barrier-free fully-vectorized MFMA loop
    dim3 g1(HW_ / 64, B_);
    kv_conv_mfma<<<g1, dim3(256), 0, stream>>>(key1_b, value_b, out);

    // K2: attention, channel-split across waves
    dim3 g2(HW_ / 64, B_);
    attn_kernel<<<g2, dim3(256), 0, stream>>>(dw_w, dw_b, k3_w, k3_b, out);

    // K3: output projection + residual (register-batched)
    dim3 g3(HW_ / 128, 3, B_);
    out_conv_mfma<4><<<g3, dim3(256), 0, stream>>>(out_w, out_b, x, out, 128);

    dim3 g4(HW_ / 64, 1, B_);
    out_conv_mfma<2><<<g4, dim3(256), 0, stream>>>(out_w, out_b, x, out, 0);
}

// Round 4
// 407.866 us; speedup vs baseline: 1.1621x; 1.0458x over previous
//
#include <hip/hip_runtime.h>

#define B_ 8
#define C_ 512
#define H_ 96
#define W_ 96
#define HW_ (H_ * W_)   // 9216
#define CK_ 64

typedef __attribute__((ext_vector_type(8))) short bf16x8;
typedef __attribute__((ext_vector_type(4))) float f32x4;

// outbuf channel map per batch b (fp32 plane units):
//   ch   0.. 63 : y            (written K2/attn, read K3/out_conv)
//   ch  64..191 : kv (k|v)     (written K1, read K2, dead after)
//   ch 192..447 : xpk bf16     (written pack_x, read K1, dead after; clobbered by out_conv p1)
//   b=0 ch 448..452 : wpk bf16 (written pack_w, read K1, dead after)
#define XPK_CH 192
#define WPK_OFF ((size_t)448 * HW_)

__device__ __forceinline__ short f2bf(float f) {
    union { float f; unsigned u; } v; v.f = f;
    unsigned r = v.u + 0x7fffu + ((v.u >> 16) & 1u);
    return (short)(r >> 16);
}

__device__ __forceinline__ bf16x8 cvt8(float4 a, float4 b) {
    bf16x8 s;
    s[0] = f2bf(a.x); s[1] = f2bf(a.y); s[2] = f2bf(a.z); s[3] = f2bf(a.w);
    s[4] = f2bf(b.x); s[5] = f2bf(b.y); s[6] = f2bf(b.z); s[7] = f2bf(b.w);
    return s;
}

// ---------------------------------------------------------------------------
// Kernel 0a: pack [key1_w ; value_w] (128 x 512 fp32) -> bf16 fragment order
// ---------------------------------------------------------------------------
__global__ void pack_w_kernel(const float* __restrict__ key1_w,
                              const float* __restrict__ value_w,
                              float* __restrict__ outbuf)
{
    const int idx = blockIdx.x * 256 + threadIdx.x;   // 0..8191 = (c8, oc)
    const int c8  = idx >> 7;
    const int oc  = idx & 127;
    const float* src = (oc < 64) ? (key1_w + (size_t)oc * C_)
                                 : (value_w + (size_t)(oc - 64) * C_);
    float4 f0 = *(const float4*)(src + c8 * 8);
    float4 f1 = *(const float4*)(src + c8 * 8 + 4);
    short* wpk = (short*)(outbuf + WPK_OFF);
    *(bf16x8*)(wpk + (size_t)idx * 8) = cvt8(f0, f1);
}

// ---------------------------------------------------------------------------
// Kernel 0b: pack x (fp32 [b][c][px]) -> bf16 fragment order
//   xpk[b][c8][px][j] = bf16(x[b][c8*8 + j][px]),  c8 = 0..63
// ---------------------------------------------------------------------------
__global__ __launch_bounds__(256)
void pack_x_kernel(const float* __restrict__ x, float* __restrict__ outbuf)
{
    const int px = blockIdx.x * 256 + threadIdx.x;   // grid.x = 36
    const int c8 = blockIdx.y;                        // 0..63
    const int b  = blockIdx.z;                        // 0..7
    const float* src = x + ((size_t)b * C_ + c8 * 8) * HW_ + px;
    float f[8];
#pragma unroll
    for (int j = 0; j < 8; ++j) f[j] = src[(size_t)j * HW_];
    bf16x8 s;
#pragma unroll
    for (int j = 0; j < 8; ++j) s[j] = f2bf(f[j]);
    short* xpk = (short*)(outbuf + (size_t)b * C_ * HW_ + (size_t)XPK_CH * HW_);
    *(bf16x8*)(xpk + ((size_t)c8 * HW_ + px) * 8) = s;
}

// ---------------------------------------------------------------------------
// Kernel 1 (MFMA): kv[o][px] = W[o][c] @ x[c][px];  o<64: relu(key1)+b, else value+b
// Unchanged this round.
// ---------------------------------------------------------------------------
__global__ __launch_bounds__(256, 4)
void kv_conv_mfma(const float* __restrict__ key1_b,
                  const float* __restrict__ value_b,
                  float* __restrict__ outbuf)
{
    const int b    = blockIdx.y;
    const int px0  = blockIdx.x * 64;
    const int tid  = threadIdx.x;
    const int lane = tid & 63;
    const int w    = tid >> 6;
    const int wm   = w & 1;      // oc half (64)
    const int wn   = w >> 1;     // px half (32)
    const int l15  = lane & 15;
    const int q    = lane >> 4;

    __shared__ float s_bias[128];
    if (tid < 128) s_bias[tid] = (tid < 64) ? key1_b[tid] : value_b[tid - 64];
    __syncthreads();             // only barrier in the kernel

    f32x4 acc[4][2];
#pragma unroll
    for (int i = 0; i < 4; ++i)
#pragma unroll
        for (int j = 0; j < 2; ++j) acc[i][j] = (f32x4){0.f, 0.f, 0.f, 0.f};

    const short* wpk = (const short*)(outbuf + WPK_OFF);
    const short* xpk = (const short*)(outbuf + (size_t)b * C_ * HW_ + (size_t)XPK_CH * HW_);
    const short* apk = wpk + ((size_t)q * 128 + wm * 64 + l15) * 8;
    const short* bpk = xpk + ((size_t)q * HW_ + px0 + wn * 32 + l15) * 8;

    for (int i = 0; i < 16; ++i) {            // kc = 32*i
        bf16x8 af[4];
#pragma unroll
        for (int mt = 0; mt < 4; ++mt)
            af[mt] = *(const bf16x8*)(apk + ((size_t)i * 512 + mt * 16) * 8);
        bf16x8 bf[2];
#pragma unroll
        for (int nt = 0; nt < 2; ++nt)
            bf[nt] = *(const bf16x8*)(bpk + ((size_t)(i * 4) * HW_ + nt * 16) * 8);
#pragma unroll
        for (int nt = 0; nt < 2; ++nt)
#pragma unroll
            for (int mt = 0; mt < 4; ++mt)
                acc[mt][nt] = __builtin_amdgcn_mfma_f32_16x16x32_bf16(af[mt], bf[nt], acc[mt][nt], 0, 0, 0);
    }

    float* kvb = outbuf + ((size_t)b * C_ + 64) * HW_ + px0;
#pragma unroll
    for (int mt = 0; mt < 4; ++mt) {
#pragma unroll
        for (int r = 0; r < 4; ++r) {
            int oc = wm * 64 + mt * 16 + q * 4 + r;
            float bias = s_bias[oc];
#pragma unroll
            for (int nt = 0; nt < 2; ++nt) {
                float v = acc[mt][nt][r] + bias;
                if (oc < 64) v = fmaxf(v, 0.f);
                kvb[(size_t)oc * HW_ + wn * 32 + nt * 16 + l15] = v;
            }
        }
    }
}

// ---------------------------------------------------------------------------
// Kernel 2 (v3): attention with LDS-tiled 9-tap gather.
// Block = 256 px; taps for the whole block live in flat window [px0-97, px0+353)
// (450 words/channel). Stage 16 channels/chunk into LDS (double-buffered,
// reg-staged T14-style), serve all 9 taps from LDS. kv is read ONCE from
// global (1.76x halo redundancy) instead of ~9x gather re-reads.
// 4 key chunks -> logits -> softmax -> 4 value chunks -> y.
// ---------------------------------------------------------------------------
#define ATPX  256
#define AHALO 97
#define AWIN  (ATPX + 2 * AHALO)   // 450
#define ACH   16
#define ALD   29                   // ceil(ACH*AWIN / 256)

__global__ __launch_bounds__(256, 2)
void attn_kernel(const float* __restrict__ dw_w, const float* __restrict__ dw_b,
                 const float* __restrict__ k3_w, const float* __restrict__ k3_b,
                 float* __restrict__ outbuf)
{
    const int b   = blockIdx.y;
    const int px0 = blockIdx.x * ATPX;
    const int tid = threadIdx.x;
    const int hw  = px0 + tid;
    const int h   = hw / W_;
    const int w   = hw % W_;

    __shared__ float s_dw[CK_ * 9];
    __shared__ float s_dwb[CK_];
    __shared__ float s_k3[9 * CK_];
    __shared__ float s_k3b[16];
    __shared__ float s_tile[2][ACH * AWIN];

    for (int i = tid; i < CK_ * 9; i += 256) {
        s_dw[i] = dw_w[i];
        s_k3[i] = k3_w[i];
    }
    if (tid < CK_) s_dwb[tid] = dw_b[tid];
    if (tid < 9)   s_k3b[tid] = k3_b[tid];

    // per-thread tap offsets into the LDS window (clamped to 0 when invalid)
    int  offl[9];
    bool valid[9];
#pragma unroll
    for (int t = 0; t < 9; ++t) {
        int dy = t / 3 - 1, dx = t % 3 - 1;
        int hh = h + dy, ww = w + dx;
        valid[t] = (hh >= 0) && (hh < H_) && (ww >= 0) && (ww < W_);
        offl[t]  = valid[t] ? (hh * W_ + ww) - (px0 - AHALO) : 0;
    }

    const float* kvbase = outbuf + ((size_t)b * C_ + 64) * HW_;
    float* yb = outbuf + (size_t)b * C_ * HW_;

    float rs[ALD];

    // prologue: load + write chunk 0
#pragma unroll
    for (int j = 0; j < ALD; ++j) {
        int idx = tid + j * 256;
        float v = 0.f;
        if (idx < ACH * AWIN) {
            int ch   = idx / AWIN;
            int p    = idx - ch * AWIN;
            int flat = px0 - AHALO + p;
            if (flat >= 0 && flat < HW_) v = kvbase[(size_t)ch * HW_ + flat];
        }
        rs[j] = v;
    }
#pragma unroll
    for (int j = 0; j < ALD; ++j) {
        int idx = tid + j * 256;
        if (idx < ACH * AWIN) s_tile[0][idx] = rs[j];
    }
    __syncthreads();

    float logits[9];
#pragma unroll
    for (int t = 0; t < 9; ++t) logits[t] = s_k3b[t];
    float wt[9];

    for (int ck = 0; ck < 8; ++ck) {
        const int buf = ck & 1;

        // issue next chunk's global loads (latency hides under compute)
        if (ck < 7) {
            const float* pb = kvbase + (size_t)(ck + 1) * ACH * HW_;
#pragma unroll
            for (int j = 0; j < ALD; ++j) {
                int idx = tid + j * 256;
                float v = 0.f;
                if (idx < ACH * AWIN) {
                    int ch   = idx / AWIN;
                    int p    = idx - ch * AWIN;
                    int flat = px0 - AHALO + p;
                    if (flat >= 0 && flat < HW_) v = pb[(size_t)ch * HW_ + flat];
                }
                rs[j] = v;
            }
        }

        if (ck < 4) {
            // key chunk: depthwise 3x3 + key3 accumulation into logits
#pragma unroll 4
            for (int ci = 0; ci < ACH; ++ci) {
                int c = ck * ACH + ci;
                const float* tp = &s_tile[buf][ci * AWIN];
                float d = s_dwb[c];
#pragma unroll
                for (int t = 0; t < 9; ++t) {
                    float val = valid[t] ? tp[offl[t]] : 0.f;
                    d = fmaf(s_dw[c * 9 + t], val, d);
                }
#pragma unroll
                for (int t = 0; t < 9; ++t)
                    logits[t] = fmaf(s_k3[t * CK_ + c], d, logits[t]);
            }
        } else {
            // value chunk: weighted 9-tap aggregation -> y
#pragma unroll 4
            for (int ci = 0; ci < ACH; ++ci) {
                int cv = (ck - 4) * ACH + ci;
                const float* tp = &s_tile[buf][ci * AWIN];
                float a = 0.f;
#pragma unroll
                for (int t = 0; t < 9; ++t) {
                    float val = valid[t] ? tp[offl[t]] : 0.f;
                    a = fmaf(wt[t], val, a);
                }
                yb[(size_t)cv * HW_ + hw] = a;
            }
        }

        if (ck == 3) {
            // softmax over the 9 taps
            float m = logits[0];
#pragma unroll
            for (int t = 1; t < 9; ++t) m = fmaxf(m, logits[t]);
            float s = 0.f;
#pragma unroll
            for (int t = 0; t < 9; ++t) { wt[t] = __expf(logits[t] - m); s += wt[t]; }
            float inv = 1.f / s;
#pragma unroll
            for (int t = 0; t < 9; ++t) wt[t] *= inv;
        }

        if (ck < 7) {
            __syncthreads();   // all reads of buf^1 (chunk ck-1) finished 2 syncs ago; writes of buf done
#pragma unroll
            for (int j = 0; j < ALD; ++j) {
                int idx = tid + j * 256;
                if (idx < ACH * AWIN) s_tile[buf ^ 1][idx] = rs[j];
            }
            __syncthreads();
        }
    }
}

// ---------------------------------------------------------------------------
// Kernel 3 (MFMA): out = x + out_b + out_w[512x64] @ y.  Register-batched.
// Unchanged this round.
// ---------------------------------------------------------------------------
template<int NT>
__global__ __launch_bounds__(256, 2)
void out_conv_mfma(const float* __restrict__ out_w, const float* __restrict__ out_b,
                   const float* __restrict__ x, float* __restrict__ outbuf, int oc_base)
{
    const int b    = blockIdx.z;
    const int o0   = oc_base + blockIdx.y * 128;
    const int px0  = blockIdx.x * (NT * 32);
    const int tid  = threadIdx.x;
    const int lane = tid & 63;
    const int w    = tid >> 6;
    const int wm   = w & 1;
    const int wn   = w >> 1;
    const int l15  = lane & 15;
    const int q    = lane >> 4;

    __shared__ short Ws[128][72];   // [oc][cv] bf16, stride 72 (144 B, 16B-aligned)
    __shared__ float s_bias[128];

    {   // stage out_w tile (128 x 64) -> bf16 LDS
        int row = tid & 127, half = tid >> 7;
        const float* wp = out_w + (size_t)(o0 + row) * CK_ + half * 32;
        float4 f0 = *(const float4*)(wp);
        float4 f1 = *(const float4*)(wp + 4);
        float4 f2 = *(const float4*)(wp + 8);
        float4 f3 = *(const float4*)(wp + 12);
        float4 f4 = *(const float4*)(wp + 16);
        float4 f5 = *(const float4*)(wp + 20);
        float4 f6 = *(const float4*)(wp + 24);
        float4 f7 = *(const float4*)(wp + 28);
        *(bf16x8*)&Ws[row][half * 32]      = cvt8(f0, f1);
        *(bf16x8*)&Ws[row][half * 32 + 8]  = cvt8(f2, f3);
        *(bf16x8*)&Ws[row][half * 32 + 16] = cvt8(f4, f5);
        *(bf16x8*)&Ws[row][half * 32 + 24] = cvt8(f6, f7);
    }
    if (tid < 128) s_bias[tid] = out_b[o0 + tid];
    __syncthreads();

    bf16x8 af[2][4];
#pragma unroll
    for (int kc2 = 0; kc2 < 2; ++kc2)
#pragma unroll
        for (int mt = 0; mt < 4; ++mt)
            af[kc2][mt] = *(bf16x8*)&Ws[wm * 64 + mt * 16 + l15][kc2 * 32 + q * 8];

    const float* yb = outbuf + (size_t)b * C_ * HW_ + px0;
    float yv[2][NT][8];
#pragma unroll
    for (int kc2 = 0; kc2 < 2; ++kc2)
#pragma unroll
        for (int nt = 0; nt < NT; ++nt) {
            const float* yp = yb + (size_t)(kc2 * 32 + q * 8) * HW_
                                 + wn * (NT * 16) + nt * 16 + l15;
#pragma unroll
            for (int j = 0; j < 8; ++j) yv[kc2][nt][j] = yp[(size_t)j * HW_];
        }

    f32x4 acc[4][NT];
#pragma unroll
    for (int i = 0; i < 4; ++i)
#pragma unroll
        for (int j = 0; j < NT; ++j) acc[i][j] = (f32x4){0.f, 0.f, 0.f, 0.f};

#pragma unroll
    for (int kc2 = 0; kc2 < 2; ++kc2)
#pragma unroll
        for (int nt = 0; nt < NT; ++nt) {
            bf16x8 bf;
#pragma unroll
            for (int j = 0; j < 8; ++j) bf[j] = f2bf(yv[kc2][nt][j]);
#pragma unroll
            for (int mt = 0; mt < 4; ++mt)
                acc[mt][nt] = __builtin_amdgcn_mfma_f32_16x16x32_bf16(af[kc2][mt], bf, acc[mt][nt], 0, 0, 0);
        }

    const float* xb = x + (size_t)b * C_ * HW_ + px0;
    float xv[4][4][NT];
#pragma unroll
    for (int mt = 0; mt < 4; ++mt)
#pragma unroll
        for (int r = 0; r < 4; ++r) {
            int oc = o0 + wm * 64 + mt * 16 + q * 4 + r;
#pragma unroll
            for (int nt = 0; nt < NT; ++nt)
                xv[mt][r][nt] = xb[(size_t)oc * HW_ + wn * (NT * 16) + nt * 16 + l15];
        }

    if (NT == 2) __syncthreads();   // phase 2 only: all y reads before any store

    float* ob = outbuf + (size_t)b * C_ * HW_ + px0;
#pragma unroll
    for (int mt = 0; mt < 4; ++mt) {
#pragma unroll
        for (int r = 0; r < 4; ++r) {
            int ol   = wm * 64 + mt * 16 + q * 4 + r;
            int oc   = o0 + ol;
            float bias = s_bias[ol];
#pragma unroll
            for (int nt = 0; nt < NT; ++nt) {
                size_t idx = (size_t)oc * HW_ + wn * (NT * 16) + nt * 16 + l15;
                ob[idx] = acc[mt][nt][r] + bias + xv[mt][r][nt];
            }
        }
    }
}

extern "C" void kernel_launch(void* const* d_in, const int* in_sizes, int n_in,
                              void* d_out, int out_size, void* d_ws, size_t ws_size,
                              hipStream_t stream)
{
    const float* x       = (const float*)d_in[0];
    const float* key1_w  = (const float*)d_in[1];
    const float* key1_b  = (const float*)d_in[2];
    const float* dw_w    = (const float*)d_in[3];
    const float* dw_b    = (const float*)d_in[4];
    const float* k3_w    = (const float*)d_in[5];
    const float* k3_b    = (const float*)d_in[6];
    const float* value_w = (const float*)d_in[7];
    const float* value_b = (const float*)d_in[8];
    const float* out_w   = (const float*)d_in[9];
    const float* out_b   = (const float*)d_in[10];
    float* out = (float*)d_out;

    // K0: pack weights + x into bf16 fragment order (outbuf dead zones)
    pack_w_kernel<<<dim3(32), dim3(256), 0, stream>>>(key1_w, value_w, out);
    pack_x_kernel<<<dim3(HW_ / 256, 64, B_), dim3(256), 0, stream>>>(x, out);

    // K1: kv 1x1 convs, barrier-free fully-vectorized MFMA loop
    dim3 g1(HW_ / 64, B_);
    kv_conv_mfma<<<g1, dim3(256), 0, stream>>>(key1_b, value_b, out);

    // K2: attention, LDS-tiled gather
    dim3 g2(HW_ / ATPX, B_);
    attn_kernel<<<g2, dim3(256), 0, stream>>>(dw_w, dw_b, k3_w, k3_b, out);

    // K3: output projection + residual (register-batched)
    dim3 g3(HW_ / 128, 3, B_);
    out_conv_mfma<4><<<g3, dim3(256), 0, stream>>>(out_w, out_b, x, out, 128);

    dim3 g4(HW_ / 64, 1, B_);
    out_conv_mfma<2><<<g4, dim3(256), 0, stream>>>(out_w, out_b, x, out, 0);
}